// Round 3
// baseline (208.076 us; speedup 1.0000x reference)
//
#include <hip/hip_runtime.h>
#include <math.h>

// Problem constants (from reference)
#define BB 256      // batch
#define DD 1024     // feat dim
#define AA 1024     // ada dim
#define RR 8        // rank
#define II 1024     // inter dim
#define NOUT (2*DD*RR)  // 16384
#define LN_EPS 1e-5f

typedef __attribute__((ext_vector_type(8))) short bf16x8;   // 8 bf16 = 4 VGPRs
typedef __attribute__((ext_vector_type(4))) float f32x4;    // MFMA 16x16 acc

typedef const __attribute__((address_space(1))) unsigned int gu32_t;
typedef __attribute__((address_space(3))) unsigned int lu32_t;

// async global->LDS, 16B per lane; lds base must be wave-uniform (HW adds lane*16)
__device__ __forceinline__ void glds16(void* lds, const void* g) {
    __builtin_amdgcn_global_load_lds((gu32_t*)g, (lu32_t*)lds, 16, 0, 0);
}

__device__ __forceinline__ f32x4 mfma16(bf16x8 a, bf16x8 b, f32x4 c) {
    return __builtin_amdgcn_mfma_f32_16x16x32_bf16(a, b, c, 0, 0, 0);
}

// fp32 -> bf16 RNE, bit-level
__device__ __forceinline__ unsigned short f2bf(float x) {
    unsigned int u = __float_as_uint(x);
    unsigned int r = (u + 0x7fffu + ((u >> 16) & 1u)) >> 16;
    return (unsigned short)r;
}
__device__ __forceinline__ float bf2f(unsigned short b) {
    return __uint_as_float(((unsigned int)b) << 16);
}
// split x ~= hi + lo (each bf16): ~17 mantissa bits
__device__ __forceinline__ void split2(float x, unsigned short& hi, unsigned short& lo) {
    hi = f2bf(x);
    lo = f2bf(x - bf2f(hi));
}

__device__ __forceinline__ float gelu_exact(float v) {
    return 0.5f * v * (1.0f + erff(v * 0.70710678118654752f));
}

// ---------------- LayerNorm + split(cond), split(x) ----------------
// one block per batch row, 256 threads, each owns 4 contiguous floats
__global__ __launch_bounds__(256) void ln_split_kernel(const float* __restrict__ ada,
                                                       const float* __restrict__ xp,
                                                       const float* __restrict__ gamma,
                                                       const float* __restrict__ beta,
                                                       unsigned short* __restrict__ c_hi,
                                                       unsigned short* __restrict__ c_lo,
                                                       unsigned short* __restrict__ x_hi,
                                                       unsigned short* __restrict__ x_lo) {
    const int b = blockIdx.x;
    const int tid = threadIdx.x;
    const float4 v = ((const float4*)(ada + (size_t)b * AA))[tid];

    float s  = v.x + v.y + v.z + v.w;
    float ss = v.x * v.x + v.y * v.y + v.z * v.z + v.w * v.w;
    #pragma unroll
    for (int off = 32; off; off >>= 1) {
        s  += __shfl_down(s, off);
        ss += __shfl_down(ss, off);
    }
    __shared__ float red[2][4];
    const int wid = tid >> 6, lane = tid & 63;
    if (lane == 0) { red[0][wid] = s; red[1][wid] = ss; }
    __syncthreads();
    __shared__ float stats[2];
    if (tid == 0) {
        float S  = red[0][0] + red[0][1] + red[0][2] + red[0][3];
        float SS = red[1][0] + red[1][1] + red[1][2] + red[1][3];
        float mu  = S * (1.0f / AA);
        float var = SS * (1.0f / AA) - mu * mu;
        stats[0] = mu;
        stats[1] = rsqrtf(var + LN_EPS);
    }
    __syncthreads();
    const float mu = stats[0], inv = stats[1];
    const float4 g  = ((const float4*)gamma)[tid];
    const float4 be = ((const float4*)beta)[tid];
    float o[4];
    o[0] = (v.x - mu) * inv * g.x + be.x;
    o[1] = (v.y - mu) * inv * g.y + be.y;
    o[2] = (v.z - mu) * inv * g.z + be.z;
    o[3] = (v.w - mu) * inv * g.w + be.w;
    ushort4 H, L;
    split2(o[0], H.x, L.x); split2(o[1], H.y, L.y);
    split2(o[2], H.z, L.z); split2(o[3], H.w, L.w);
    ((ushort4*)(c_hi + (size_t)b * AA))[tid] = H;
    ((ushort4*)(c_lo + (size_t)b * AA))[tid] = L;

    // split x row as well
    const float4 xv = ((const float4*)(xp + (size_t)b * DD))[tid];
    split2(xv.x, H.x, L.x); split2(xv.y, H.y, L.y);
    split2(xv.z, H.z, L.z); split2(xv.w, H.w, L.w);
    ((ushort4*)(x_hi + (size_t)b * DD))[tid] = H;
    ((ushort4*)(x_lo + (size_t)b * DD))[tid] = L;
}

// ---------------- fused small GEMMs (split-bf16 MFMA, dbuf 2-phase) ----------------
// z=0: out = x @ base   (fp32, written into d_out; final_kernel adds the rest in place)
// z=1: h = gelu(cond @ W1 + b1)  -> bf16 hi/lo planes
// M=256, N=1024, K=1024. BM=BN=64, BK=32, 256 thr = 4 waves (2x2), wave 32x32.
// LDS layout (fragment-native): [pl(2)][rowblk(4)][kch(4)][lrow(16)][8 ushorts] = 8KB/buf
__global__ __launch_bounds__(256) void gemm_small(const unsigned short* __restrict__ x_hi,
                                                  const unsigned short* __restrict__ x_lo,
                                                  const unsigned short* __restrict__ c_hi,
                                                  const unsigned short* __restrict__ c_lo,
                                                  const float* __restrict__ base,
                                                  const float* __restrict__ W1,
                                                  const float* __restrict__ b1,
                                                  float* __restrict__ outy,
                                                  unsigned short* __restrict__ h_hi,
                                                  unsigned short* __restrict__ h_lo) {
    __shared__ __align__(16) unsigned short As[2][4096];  // 8KB per buf
    __shared__ __align__(16) unsigned short Bs[2][4096];  // 8KB per buf

    const int z = blockIdx.z;
    const unsigned short* __restrict__ Ahi = z ? c_hi : x_hi;
    const unsigned short* __restrict__ Alo = z ? c_lo : x_lo;
    const float* __restrict__ Bsrc = z ? W1 : base;

    const int tid = threadIdx.x;
    const int bn = blockIdx.x * 64;
    const int bm = blockIdx.y * 64;
    const int wid = tid >> 6, l = tid & 63;
    const int wm = wid >> 1, wn = wid & 1;
    const int kg = l >> 4;            // lane k-chunk
    const int lr16 = (l & 15) * 16;   // lane-row byte offset within chunk

    f32x4 acc[2][2];
    #pragma unroll
    for (int i = 0; i < 2; i++)
        #pragma unroll
        for (int j = 0; j < 2; j++) acc[i][j] = (f32x4)0.0f;

    const int sn = l;                    // B-stage col (wave covers all 64)
    const int skq = (tid >> 6) << 2;     // B-stage k-quad: 0,4,8,12
    const int s_nblk = sn >> 4, s_lr16 = (sn & 15) * 16;

    float v[8];
    // ---- prologue: stage k-tile 0 into buf 0 ----
    #pragma unroll
    for (int h = 0; h < 2; h++)
        #pragma unroll
        for (int i = 0; i < 4; i++)
            v[h * 4 + i] = Bsrc[(size_t)(skq + 16 * h + i) * 1024 + bn + sn];
    #pragma unroll
    for (int i = 0; i < 2; i++) {
        const int ch = wid * 2 + i;                 // 0..7
        const unsigned short* src = (ch < 4) ? Ahi : Alo;
        const int row = bm + (ch & 3) * 16 + (l & 15);
        glds16((char*)As[0] + ch * 1024, src + (size_t)row * 1024 + kg * 8);
    }
    #pragma unroll
    for (int h = 0; h < 2; h++) {
        ushort4 H, L;
        split2(v[h*4+0], H.x, L.x); split2(v[h*4+1], H.y, L.y);
        split2(v[h*4+2], H.z, L.z); split2(v[h*4+3], H.w, L.w);
        const int kbyte = (skq + 16 * h) * 2;
        const int kch = kbyte >> 4, low = kbyte & 15;
        *(ushort4*)((char*)Bs[0] + ((0 * 4 + s_nblk) * 4 + kch) * 256 + s_lr16 + low) = H;
        *(ushort4*)((char*)Bs[0] + ((1 * 4 + s_nblk) * 4 + kch) * 256 + s_lr16 + low) = L;
    }
    __syncthreads();

    int cur = 0;
    for (int t = 0; t < 32; ++t) {
        const bool pf = (t < 31);
        const int k0n = (t + 1) * 32;
        if (pf) {
            #pragma unroll
            for (int h = 0; h < 2; h++)
                #pragma unroll
                for (int i = 0; i < 4; i++)
                    v[h * 4 + i] = Bsrc[(size_t)(k0n + skq + 16 * h + i) * 1024 + bn + sn];
            #pragma unroll
            for (int i = 0; i < 2; i++) {
                const int ch = wid * 2 + i;
                const unsigned short* src = (ch < 4) ? Ahi : Alo;
                const int row = bm + (ch & 3) * 16 + (l & 15);
                glds16((char*)As[cur ^ 1] + ch * 1024, src + (size_t)row * 1024 + k0n + kg * 8);
            }
        }
        // compute on cur
        {
            bf16x8 a[2][2], bb[2][2];
            #pragma unroll
            for (int pl = 0; pl < 2; pl++) {
                #pragma unroll
                for (int mi = 0; mi < 2; mi++)
                    a[pl][mi] = *(const bf16x8*)((const char*)As[cur] +
                        ((pl * 4 + wm * 2 + mi) * 4 + kg) * 256 + lr16);
                #pragma unroll
                for (int ni = 0; ni < 2; ni++)
                    bb[pl][ni] = *(const bf16x8*)((const char*)Bs[cur] +
                        ((pl * 4 + wn * 2 + ni) * 4 + kg) * 256 + lr16);
            }
            #pragma unroll
            for (int mi = 0; mi < 2; mi++)
                #pragma unroll
                for (int ni = 0; ni < 2; ni++) {
                    acc[mi][ni] = mfma16(a[0][mi], bb[0][ni], acc[mi][ni]);  // hi*hi
                    acc[mi][ni] = mfma16(a[0][mi], bb[1][ni], acc[mi][ni]);  // hi*lo
                    acc[mi][ni] = mfma16(a[1][mi], bb[0][ni], acc[mi][ni]);  // lo*hi
                }
        }
        if (pf) {
            #pragma unroll
            for (int h = 0; h < 2; h++) {
                ushort4 H, L;
                split2(v[h*4+0], H.x, L.x); split2(v[h*4+1], H.y, L.y);
                split2(v[h*4+2], H.z, L.z); split2(v[h*4+3], H.w, L.w);
                const int kbyte = (skq + 16 * h) * 2;
                const int kch = kbyte >> 4, low = kbyte & 15;
                *(ushort4*)((char*)Bs[cur ^ 1] + ((0 * 4 + s_nblk) * 4 + kch) * 256 + s_lr16 + low) = H;
                *(ushort4*)((char*)Bs[cur ^ 1] + ((1 * 4 + s_nblk) * 4 + kch) * 256 + s_lr16 + low) = L;
            }
        }
        __syncthreads();
        cur ^= 1;
    }

    // epilogue: C row = (l>>4)*4 + j, col = l&15 within each 16x16
    #pragma unroll
    for (int mi = 0; mi < 2; mi++) {
        #pragma unroll
        for (int ni = 0; ni < 2; ni++) {
            const int row0 = bm + wm * 32 + mi * 16 + kg * 4;
            const int col  = bn + wn * 32 + ni * 16 + (l & 15);
            #pragma unroll
            for (int j = 0; j < 4; j++) {
                float val = acc[mi][ni][j];
                if (z == 0) {
                    outy[(size_t)(row0 + j) * 1024 + col] = val;
                } else {
                    float g = gelu_exact(val + b1[col]);
                    unsigned short hi, lo;
                    split2(g, hi, lo);
                    h_hi[(size_t)(row0 + j) * 1024 + col] = hi;
                    h_lo[(size_t)(row0 + j) * 1024 + col] = lo;
                }
            }
        }
    }
}

// ---------------- big GEMM: w = h @ W2 + b2 (split-bf16 MFMA, dbuf 2-phase) ----------------
// M=256(=BM), N=16384, K=1024. BN=64, BK=32, 512 thr = 8 waves, wave tile 32x64.
// A LDS: [pl(2)][rowblk(16)][kch(4)][lrow(16)][8] = 32KB/buf; B: [pl(2)][nblk(4)][kch(4)][16][8] = 8KB/buf.
__global__ __launch_bounds__(512) void gemm_big(const unsigned short* __restrict__ Ahi,
                                                const unsigned short* __restrict__ Alo,
                                                const float* __restrict__ Bm,
                                                const float* __restrict__ bias,
                                                float* __restrict__ Cm) {
    __shared__ __align__(16) unsigned short As[2][16384];  // 32KB per buf
    __shared__ __align__(16) unsigned short Bs[2][4096];   // 8KB per buf

    const int tid = threadIdx.x;
    const int bn  = blockIdx.x * 64;
    const int wid = tid >> 6, l = tid & 63;
    const int kg = l >> 4;
    const int lr16 = (l & 15) * 16;

    f32x4 acc[2][4];
    #pragma unroll
    for (int i = 0; i < 2; i++)
        #pragma unroll
        for (int j = 0; j < 4; j++) acc[i][j] = (f32x4)0.0f;

    const int sn = l;                 // B-stage col
    const int skq = wid * 4;          // B-stage k-quad: 0..28
    const int s_nblk = sn >> 4, s_lr16 = (sn & 15) * 16;
    const int s_kbyte = skq * 2;
    const int s_kch = s_kbyte >> 4, s_low = s_kbyte & 15;

    float v[4];
    // ---- prologue: stage k-tile 0 into buf 0 ----
    #pragma unroll
    for (int i = 0; i < 4; i++)
        v[i] = Bm[(size_t)(skq + i) * NOUT + bn + sn];
    #pragma unroll
    for (int i = 0; i < 4; i++) {
        const int ch = wid * 4 + i;                 // 0..31
        const unsigned short* src = (ch < 16) ? Ahi : Alo;
        const int row = (ch & 15) * 16 + (l & 15);
        glds16((char*)As[0] + ch * 1024, src + (size_t)row * II + kg * 8);
    }
    {
        ushort4 H, L;
        split2(v[0], H.x, L.x); split2(v[1], H.y, L.y);
        split2(v[2], H.z, L.z); split2(v[3], H.w, L.w);
        *(ushort4*)((char*)Bs[0] + ((0 * 4 + s_nblk) * 4 + s_kch) * 256 + s_lr16 + s_low) = H;
        *(ushort4*)((char*)Bs[0] + ((1 * 4 + s_nblk) * 4 + s_kch) * 256 + s_lr16 + s_low) = L;
    }
    __syncthreads();

    int cur = 0;
    for (int t = 0; t < 32; ++t) {
        const bool pf = (t < 31);
        const int k0n = (t + 1) * 32;
        if (pf) {
            #pragma unroll
            for (int i = 0; i < 4; i++)
                v[i] = Bm[(size_t)(k0n + skq + i) * NOUT + bn + sn];
            #pragma unroll
            for (int i = 0; i < 4; i++) {
                const int ch = wid * 4 + i;
                const unsigned short* src = (ch < 16) ? Ahi : Alo;
                const int row = (ch & 15) * 16 + (l & 15);
                glds16((char*)As[cur ^ 1] + ch * 1024, src + (size_t)row * II + k0n + kg * 8);
            }
        }
        // compute on cur: wave rowblks {2*wid, 2*wid+1}, all 4 nblks
        {
            bf16x8 a[2][2], bb[2][4];
            #pragma unroll
            for (int pl = 0; pl < 2; pl++) {
                #pragma unroll
                for (int mi = 0; mi < 2; mi++)
                    a[pl][mi] = *(const bf16x8*)((const char*)As[cur] +
                        ((pl * 16 + wid * 2 + mi) * 4 + kg) * 256 + lr16);
                #pragma unroll
                for (int ni = 0; ni < 4; ni++)
                    bb[pl][ni] = *(const bf16x8*)((const char*)Bs[cur] +
                        ((pl * 4 + ni) * 4 + kg) * 256 + lr16);
            }
            #pragma unroll
            for (int mi = 0; mi < 2; mi++)
                #pragma unroll
                for (int ni = 0; ni < 4; ni++) {
                    acc[mi][ni] = mfma16(a[0][mi], bb[0][ni], acc[mi][ni]);  // hi*hi
                    acc[mi][ni] = mfma16(a[0][mi], bb[1][ni], acc[mi][ni]);  // hi*lo
                    acc[mi][ni] = mfma16(a[1][mi], bb[0][ni], acc[mi][ni]);  // lo*hi
                }
        }
        if (pf) {
            ushort4 H, L;
            split2(v[0], H.x, L.x); split2(v[1], H.y, L.y);
            split2(v[2], H.z, L.z); split2(v[3], H.w, L.w);
            *(ushort4*)((char*)Bs[cur ^ 1] + ((0 * 4 + s_nblk) * 4 + s_kch) * 256 + s_lr16 + s_low) = H;
            *(ushort4*)((char*)Bs[cur ^ 1] + ((1 * 4 + s_nblk) * 4 + s_kch) * 256 + s_lr16 + s_low) = L;
        }
        __syncthreads();
        cur ^= 1;
    }

    // epilogue: + bias, fp32 store
    #pragma unroll
    for (int mi = 0; mi < 2; mi++) {
        #pragma unroll
        for (int ni = 0; ni < 4; ni++) {
            const int row0 = wid * 32 + mi * 16 + kg * 4;
            const int col  = bn + ni * 16 + (l & 15);
            const float bv = bias[col];
            #pragma unroll
            for (int j = 0; j < 4; j++)
                Cm[(size_t)(row0 + j) * NOUT + col] = acc[mi][ni][j] + bv;
        }
    }
}

// ---------------- t[b,r] = sum_c x[b,c] * x_a[b,c,r] ----------------
__global__ __launch_bounds__(256) void t_kernel(const float* __restrict__ x,
                                                const float* __restrict__ w,
                                                float* __restrict__ tmat) {
    const int b = blockIdx.x;
    const int tid = threadIdx.x;
    const float* wa = w + (size_t)b * NOUT;  // x_a half
    const float4 xv = ((const float4*)(x + (size_t)b * DD))[tid];
    const float xs[4] = {xv.x, xv.y, xv.z, xv.w};

    float acc[RR] = {};
    #pragma unroll
    for (int i = 0; i < 4; i++) {
        const int c = tid * 4 + i;
        const float4 w0 = *(const float4*)&wa[c * RR];
        const float4 w1 = *(const float4*)&wa[c * RR + 4];
        acc[0] = fmaf(xs[i], w0.x, acc[0]);
        acc[1] = fmaf(xs[i], w0.y, acc[1]);
        acc[2] = fmaf(xs[i], w0.z, acc[2]);
        acc[3] = fmaf(xs[i], w0.w, acc[3]);
        acc[4] = fmaf(xs[i], w1.x, acc[4]);
        acc[5] = fmaf(xs[i], w1.y, acc[5]);
        acc[6] = fmaf(xs[i], w1.z, acc[6]);
        acc[7] = fmaf(xs[i], w1.w, acc[7]);
    }
    __shared__ float red[4][RR];
    const int wid = tid >> 6, lane = tid & 63;
    #pragma unroll
    for (int r = 0; r < RR; r++) {
        float vv = acc[r];
        #pragma unroll
        for (int off = 32; off; off >>= 1) vv += __shfl_down(vv, off);
        if (lane == 0) red[wid][r] = vv;
    }
    __syncthreads();
    if (tid < RR) {
        tmat[b * RR + tid] = red[0][tid] + red[1][tid] + red[2][tid] + red[3][tid];
    }
}

// ---------------- out = x + y(in out) + sum_r t[b,r]*x_b[b,o,r] ----------------
__global__ __launch_bounds__(256) void final_kernel(const float* __restrict__ x,
                                                    const float* __restrict__ w,
                                                    const float* __restrict__ tmat,
                                                    float* __restrict__ out) {
    const int b = blockIdx.x;
    const int tid = threadIdx.x;
    float tr[RR];
    #pragma unroll
    for (int r = 0; r < RR; r++) tr[r] = tmat[b * RR + r];

    const float* wb = w + (size_t)b * NOUT + DD * RR;  // x_b half
    const int o0 = tid * 4;
    const float4 xv = *(const float4*)&x[(size_t)b * DD + o0];
    const float4 yv = *(const float4*)&out[(size_t)b * DD + o0];  // y = x@base, in place

    float vals[4];
    #pragma unroll
    for (int i = 0; i < 4; i++) {
        const float4 w0 = *(const float4*)&wb[(o0 + i) * RR];
        const float4 w1 = *(const float4*)&wb[(o0 + i) * RR + 4];
        vals[i] = tr[0] * w0.x + tr[1] * w0.y + tr[2] * w0.z + tr[3] * w0.w
                + tr[4] * w1.x + tr[5] * w1.y + tr[6] * w1.z + tr[7] * w1.w;
    }
    float4 o;
    o.x = xv.x + yv.x + vals[0];
    o.y = xv.y + yv.y + vals[1];
    o.z = xv.z + yv.z + vals[2];
    o.w = xv.w + yv.w + vals[3];
    *(float4*)&out[(size_t)b * DD + o0] = o;
}

extern "C" void kernel_launch(void* const* d_in, const int* in_sizes, int n_in,
                              void* d_out, int out_size, void* d_ws, size_t ws_size,
                              hipStream_t stream) {
    const float* x     = (const float*)d_in[0];
    const float* ada   = (const float*)d_in[1];
    const float* base  = (const float*)d_in[2];
    const float* gamma = (const float*)d_in[3];
    const float* beta  = (const float*)d_in[4];
    const float* W1    = (const float*)d_in[5];
    const float* b1    = (const float*)d_in[6];
    const float* W2    = (const float*)d_in[7];
    const float* b2    = (const float*)d_in[8];
    float* out = (float*)d_out;

    // ws layout: total 19,931,136 B (== proven round-1 footprint)
    char* wsb = (char*)d_ws;
    float* w = (float*)(wsb);                                   // 16,777,216
    unsigned short* h_hi = (unsigned short*)(wsb + 16777216);   //    524,288
    unsigned short* h_lo = (unsigned short*)(wsb + 17301504);   //    524,288
    unsigned short* x_hi = (unsigned short*)(wsb + 17825792);   //    524,288
    unsigned short* x_lo = (unsigned short*)(wsb + 18350080);   //    524,288
    unsigned short* c_hi = (unsigned short*)(wsb + 18874368);   //    524,288
    unsigned short* c_lo = (unsigned short*)(wsb + 19398656);   //    524,288
    float* tmat = (float*)(wsb + 19922944);                     //      8,192

    // 1) LayerNorm -> cond planes; split x -> planes
    ln_split_kernel<<<BB, 256, 0, stream>>>(ada, x, gamma, beta, c_hi, c_lo, x_hi, x_lo);

    // 2) fused: z=0 out = x@base (y, in place) ; z=1 h = gelu(cond@W1+b1) -> planes
    gemm_small<<<dim3(DD / 64, BB / 64, 2), 256, 0, stream>>>(
        x_hi, x_lo, c_hi, c_lo, base, W1, b1, out, h_hi, h_lo);

    // 3) w = h @ W2 + b2  (dominant GEMM)
    gemm_big<<<dim3(NOUT / 64, 1), 512, 0, stream>>>(h_hi, h_lo, W2, b2, w);

    // 4) t[b,r] = sum_c x[b,c] * x_a[b,c,r]
    t_kernel<<<BB, 256, 0, stream>>>(x, w, tmat);

    // 5) out = x + y + sum_r t[b,r] * x_b[b,:,r]
    final_kernel<<<BB, 256, 0, stream>>>(x, w, tmat, out);
}

// Round 4
// 202.266 us; speedup vs baseline: 1.0287x; 1.0287x over previous
//
#include <hip/hip_runtime.h>
#include <math.h>

// Problem constants
#define BB 256      // batch
#define DD 1024     // feat dim
#define AA 1024     // ada dim
#define RR 8        // rank
#define II 1024     // inter dim
#define NOUT (2*DD*RR)  // 16384
#define LN_EPS 1e-5f

typedef __attribute__((ext_vector_type(8))) short bf16x8;   // 8 bf16 = 4 VGPRs
typedef __attribute__((ext_vector_type(4))) float f32x4;    // MFMA 16x16 acc

typedef const __attribute__((address_space(1))) unsigned int gu32_t;
typedef __attribute__((address_space(3))) unsigned int lu32_t;

// async global->LDS, 16B/lane; LDS base wave-uniform (HW adds lane*16), global addr per-lane
__device__ __forceinline__ void glds16(void* lds, const void* g) {
    __builtin_amdgcn_global_load_lds((gu32_t*)g, (lu32_t*)lds, 16, 0, 0);
}

__device__ __forceinline__ f32x4 mfma16(bf16x8 a, bf16x8 b, f32x4 c) {
    return __builtin_amdgcn_mfma_f32_16x16x32_bf16(a, b, c, 0, 0, 0);
}

__device__ __forceinline__ unsigned short f2bf(float x) {
    unsigned int u = __float_as_uint(x);
    unsigned int r = (u + 0x7fffu + ((u >> 16) & 1u)) >> 16;
    return (unsigned short)r;
}
__device__ __forceinline__ float bf2f(unsigned short b) {
    return __uint_as_float(((unsigned int)b) << 16);
}
__device__ __forceinline__ void split2(float x, unsigned short& hi, unsigned short& lo) {
    hi = f2bf(x);
    lo = f2bf(x - bf2f(hi));
}

__device__ __forceinline__ float gelu_exact(float v) {
    return 0.5f * v * (1.0f + erff(v * 0.70710678118654752f));
}

// ---------------- LayerNorm + split(cond), split(x) ----------------
__global__ __launch_bounds__(256) void ln_split_kernel(const float* __restrict__ ada,
                                                       const float* __restrict__ xp,
                                                       const float* __restrict__ gamma,
                                                       const float* __restrict__ beta,
                                                       unsigned short* __restrict__ c_hi,
                                                       unsigned short* __restrict__ c_lo,
                                                       unsigned short* __restrict__ x_hi,
                                                       unsigned short* __restrict__ x_lo) {
    const int b = blockIdx.x;
    const int tid = threadIdx.x;
    const float4 v = ((const float4*)(ada + (size_t)b * AA))[tid];

    float s  = v.x + v.y + v.z + v.w;
    float ss = v.x * v.x + v.y * v.y + v.z * v.z + v.w * v.w;
    #pragma unroll
    for (int off = 32; off; off >>= 1) {
        s  += __shfl_down(s, off);
        ss += __shfl_down(ss, off);
    }
    __shared__ float red[2][4];
    const int wid = tid >> 6, lane = tid & 63;
    if (lane == 0) { red[0][wid] = s; red[1][wid] = ss; }
    __syncthreads();
    __shared__ float stats[2];
    if (tid == 0) {
        float S  = red[0][0] + red[0][1] + red[0][2] + red[0][3];
        float SS = red[1][0] + red[1][1] + red[1][2] + red[1][3];
        float mu  = S * (1.0f / AA);
        float var = SS * (1.0f / AA) - mu * mu;
        stats[0] = mu;
        stats[1] = rsqrtf(var + LN_EPS);
    }
    __syncthreads();
    const float mu = stats[0], inv = stats[1];
    const float4 g  = ((const float4*)gamma)[tid];
    const float4 be = ((const float4*)beta)[tid];
    float o[4];
    o[0] = (v.x - mu) * inv * g.x + be.x;
    o[1] = (v.y - mu) * inv * g.y + be.y;
    o[2] = (v.z - mu) * inv * g.z + be.z;
    o[3] = (v.w - mu) * inv * g.w + be.w;
    ushort4 H, L;
    split2(o[0], H.x, L.x); split2(o[1], H.y, L.y);
    split2(o[2], H.z, L.z); split2(o[3], H.w, L.w);
    ((ushort4*)(c_hi + (size_t)b * AA))[tid] = H;
    ((ushort4*)(c_lo + (size_t)b * AA))[tid] = L;

    const float4 xv = ((const float4*)(xp + (size_t)b * DD))[tid];
    split2(xv.x, H.x, L.x); split2(xv.y, H.y, L.y);
    split2(xv.z, H.z, L.z); split2(xv.w, H.w, L.w);
    ((ushort4*)(x_hi + (size_t)b * DD))[tid] = H;
    ((ushort4*)(x_lo + (size_t)b * DD))[tid] = L;
}

// ---------------- small GEMMs: BM=32, BN=64, BK=64, 4 waves, 16 iters ----------------
// z=0: out = x @ base (fp32) ; z=1: h = gelu(cond @ W1 + b1) -> bf16 planes
// A LDS: [pl2][m2][kidx8][16lanes][16B] = 8KB/buf ; B: [pl2][nb4][kidx8][16][16B] = 16KB/buf
__global__ __launch_bounds__(256) void gemm_small(const unsigned short* __restrict__ x_hi,
                                                  const unsigned short* __restrict__ x_lo,
                                                  const unsigned short* __restrict__ c_hi,
                                                  const unsigned short* __restrict__ c_lo,
                                                  const float* __restrict__ base,
                                                  const float* __restrict__ W1,
                                                  const float* __restrict__ b1,
                                                  float* __restrict__ outy,
                                                  unsigned short* __restrict__ h_hi,
                                                  unsigned short* __restrict__ h_lo) {
    __shared__ __align__(16) unsigned short As[2][4096];   // 8KB per buf
    __shared__ __align__(16) unsigned short Bs[2][8192];   // 16KB per buf

    const int z = blockIdx.z;
    const unsigned short* __restrict__ Ahi = z ? c_hi : x_hi;
    const unsigned short* __restrict__ Alo = z ? c_lo : x_lo;
    const float* __restrict__ Bsrc = z ? W1 : base;

    const int tid = threadIdx.x;
    const int bn = blockIdx.x * 64;
    const int bm = blockIdx.y * 32;
    const int wid = tid >> 6, l = tid & 63;
    const int wn = wid;               // 4 waves along N, wave tile 32x16
    const int kg = l >> 4;
    const int lr16 = (l & 15) * 16;

    f32x4 acc[2];
    acc[0] = (f32x4)0.0f; acc[1] = (f32x4)0.0f;

    const int sn = tid & 63;
    const int s_nb = sn >> 4, s_lane16 = (sn & 15) * 16;
    const int s_k4 = (tid >> 6) * 4;   // 0,4,8,12

    float v[4][4];

    #define SB_LOAD(K0)                                                         \
        _Pragma("unroll")                                                       \
        for (int p = 0; p < 4; p++) {                                           \
            const int kq = s_k4 + p * 16;                                       \
            _Pragma("unroll")                                                   \
            for (int i = 0; i < 4; i++)                                         \
                v[p][i] = Bsrc[(size_t)((K0) + kq + i) * 1024 + bn + sn];       \
        }

    #define SB_WRITE(BUF)                                                       \
        _Pragma("unroll")                                                       \
        for (int p = 0; p < 4; p++) {                                           \
            const int kq = s_k4 + p * 16;                                       \
            const int kidx = kq >> 3, klow2 = (kq & 7) * 2;                     \
            ushort4 H, L;                                                       \
            split2(v[p][0], H.x, L.x); split2(v[p][1], H.y, L.y);               \
            split2(v[p][2], H.z, L.z); split2(v[p][3], H.w, L.w);               \
            *(ushort4*)((char*)Bs[BUF] + ((0*4 + s_nb)*8 + kidx)*256 + s_lane16 + klow2) = H; \
            *(ushort4*)((char*)Bs[BUF] + ((1*4 + s_nb)*8 + kidx)*256 + s_lane16 + klow2) = L; \
        }

    #define SA_GLDS(BUF, K0)                                                    \
        _Pragma("unroll")                                                       \
        for (int c = 0; c < 2; c++) {                                           \
            const int ch = wid * 2 + c;          /* 0..7 */                     \
            const int pl = ch >> 2, rr = ch & 3;                                \
            const int m = rr & 1, half = rr >> 1;                               \
            const unsigned short* src = (pl ? Alo : Ahi)                        \
                + (size_t)(bm + m * 16 + (l & 15)) * 1024 + (K0) + half * 32 + kg * 8; \
            glds16((char*)As[BUF] + ((pl*2 + m)*8 + half*4) * 256, src);        \
        }

    #define S_COMPUTE(BUF)                                                      \
        {                                                                       \
            _Pragma("unroll")                                                   \
            for (int s = 0; s < 2; s++) {                                       \
                bf16x8 a[2][2], bbf[2];                                         \
                _Pragma("unroll")                                               \
                for (int pl = 0; pl < 2; pl++) {                                \
                    _Pragma("unroll")                                           \
                    for (int mi = 0; mi < 2; mi++)                              \
                        a[pl][mi] = *(const bf16x8*)((const char*)As[BUF] +     \
                            ((pl*2 + mi)*8 + s*4 + kg)*256 + lr16);             \
                    bbf[pl] = *(const bf16x8*)((const char*)Bs[BUF] +           \
                            ((pl*4 + wn)*8 + s*4 + kg)*256 + lr16);             \
                }                                                               \
                _Pragma("unroll")                                               \
                for (int mi = 0; mi < 2; mi++) {                                \
                    acc[mi] = mfma16(a[0][mi], bbf[0], acc[mi]);                \
                    acc[mi] = mfma16(a[0][mi], bbf[1], acc[mi]);                \
                    acc[mi] = mfma16(a[1][mi], bbf[0], acc[mi]);                \
                }                                                               \
            }                                                                   \
        }

    // prologue
    SB_LOAD(0);
    SA_GLDS(0, 0);
    SB_WRITE(0);
    __syncthreads();

    int cur = 0;
    for (int t = 0; t < 16; ++t) {
        if (t < 15) {
            const int k0n = (t + 1) * 64;
            SB_LOAD(k0n);
            SA_GLDS(cur ^ 1, k0n);
        }
        S_COMPUTE(cur);
        if (t < 15) {
            SB_WRITE(cur ^ 1);
            __syncthreads();
        }
        cur ^= 1;
    }

    // epilogue
    #pragma unroll
    for (int mi = 0; mi < 2; mi++) {
        const int row0 = bm + mi * 16 + (l >> 4) * 4;
        const int col  = bn + wn * 16 + (l & 15);
        #pragma unroll
        for (int j = 0; j < 4; j++) {
            float val = acc[mi][j];
            if (z == 0) {
                outy[(size_t)(row0 + j) * 1024 + col] = val;
            } else {
                float g = gelu_exact(val + b1[col]);
                unsigned short hi, lo;
                split2(g, hi, lo);
                h_hi[(size_t)(row0 + j) * 1024 + col] = hi;
                h_lo[(size_t)(row0 + j) * 1024 + col] = lo;
            }
        }
    }
    #undef SB_LOAD
    #undef SB_WRITE
    #undef SA_GLDS
    #undef S_COMPUTE
}

// ---------------- big GEMM: 128x128 block, 4 waves of 64x64, BK=32, dbuf ----------------
// M=256, N=16384, K=1024. grid (128, 2) = 256 blocks.
// A LDS: [pl2][m8][kg4][16lanes][16B] = 16KB/buf ; B same = 16KB/buf; total 64KB.
__global__ __launch_bounds__(256) void gemm_big(const unsigned short* __restrict__ Ahi,
                                                const unsigned short* __restrict__ Alo,
                                                const float* __restrict__ Bm,
                                                const float* __restrict__ bias,
                                                float* __restrict__ Cm) {
    __shared__ __align__(16) unsigned short As[2][8192];   // 16KB per buf
    __shared__ __align__(16) unsigned short Bs[2][8192];

    const int tid = threadIdx.x;
    const int bn = blockIdx.x * 128;
    const int bm = blockIdx.y * 128;
    const int wid = tid >> 6, l = tid & 63;
    const int wm = wid >> 1, wn = wid & 1;   // 2x2 waves, wave tile 64x64
    const int kg = l >> 4;
    const int lr16 = (l & 15) * 16;

    f32x4 acc[4][4];
    #pragma unroll
    for (int i = 0; i < 4; i++)
        #pragma unroll
        for (int j = 0; j < 4; j++) acc[i][j] = (f32x4)0.0f;

    const int sn = tid & 127;
    const int s_nb = sn >> 4, s_lane16 = (sn & 15) * 16;
    const int s_kb = (tid >> 7) * 4;   // 0 or 4

    float v[4][4];

    #define GB_LOAD(K0)                                                         \
        _Pragma("unroll")                                                       \
        for (int p = 0; p < 4; p++) {                                           \
            const int kq = s_kb + p * 8;                                        \
            _Pragma("unroll")                                                   \
            for (int i = 0; i < 4; i++)                                         \
                v[p][i] = Bm[(size_t)((K0) + kq + i) * NOUT + bn + sn];         \
        }

    #define GB_WRITE(BUF)                                                       \
        _Pragma("unroll")                                                       \
        for (int p = 0; p < 4; p++) {                                           \
            ushort4 H, L;                                                       \
            split2(v[p][0], H.x, L.x); split2(v[p][1], H.y, L.y);               \
            split2(v[p][2], H.z, L.z); split2(v[p][3], H.w, L.w);               \
            *(ushort4*)((char*)Bs[BUF] + ((0*8 + s_nb)*4 + p)*256 + s_lane16 + s_kb*2) = H; \
            *(ushort4*)((char*)Bs[BUF] + ((1*8 + s_nb)*4 + p)*256 + s_lane16 + s_kb*2) = L; \
        }

    #define GA_GLDS(BUF, K0)                                                    \
        _Pragma("unroll")                                                       \
        for (int c = 0; c < 4; c++) {                                           \
            const int ch = wid * 4 + c;          /* 0..15 */                    \
            const int pl = ch >> 3, m = ch & 7;                                 \
            const unsigned short* src = (pl ? Alo : Ahi)                        \
                + (size_t)(bm + m * 16 + (l & 15)) * II + (K0) + kg * 8;        \
            glds16((char*)As[BUF] + ch * 1024, src);                            \
        }

    #define G_COMPUTE(BUF)                                                     \
        {                                                                       \
            bf16x8 a[2][4], bbf[2][4];                                          \
            _Pragma("unroll")                                                   \
            for (int pl = 0; pl < 2; pl++) {                                    \
                _Pragma("unroll")                                               \
                for (int mi = 0; mi < 4; mi++)                                  \
                    a[pl][mi] = *(const bf16x8*)((const char*)As[BUF] +         \
                        ((pl*8 + wm*4 + mi)*4 + kg)*256 + lr16);                \
                _Pragma("unroll")                                               \
                for (int ni = 0; ni < 4; ni++)                                  \
                    bbf[pl][ni] = *(const bf16x8*)((const char*)Bs[BUF] +       \
                        ((pl*8 + wn*4 + ni)*4 + kg)*256 + lr16);                \
            }                                                                   \
            _Pragma("unroll")                                                   \
            for (int mi = 0; mi < 4; mi++) {                                    \
                _Pragma("unroll")                                               \
                for (int ni = 0; ni < 4; ni++) {                                \
                    acc[mi][ni] = mfma16(a[0][mi], bbf[0][ni], acc[mi][ni]);    \
                    acc[mi][ni] = mfma16(a[0][mi], bbf[1][ni], acc[mi][ni]);    \
                    acc[mi][ni] = mfma16(a[1][mi], bbf[0][ni], acc[mi][ni]);    \
                }                                                               \
            }                                                                   \
        }

    // prologue
    GB_LOAD(0);
    GA_GLDS(0, 0);
    GB_WRITE(0);
    __syncthreads();

    int cur = 0;
    for (int t = 0; t < 32; ++t) {
        if (t < 31) {
            const int k0n = (t + 1) * 32;
            GB_LOAD(k0n);
            GA_GLDS(cur ^ 1, k0n);
        }
        G_COMPUTE(cur);
        if (t < 31) {
            GB_WRITE(cur ^ 1);
            __syncthreads();
        }
        cur ^= 1;
    }

    // epilogue: + bias
    #pragma unroll
    for (int mi = 0; mi < 4; mi++) {
        #pragma unroll
        for (int ni = 0; ni < 4; ni++) {
            const int row0 = bm + wm * 64 + mi * 16 + (l >> 4) * 4;
            const int col  = bn + wn * 64 + ni * 16 + (l & 15);
            const float bv = bias[col];
            #pragma unroll
            for (int j = 0; j < 4; j++)
                Cm[(size_t)(row0 + j) * NOUT + col] = acc[mi][ni][j] + bv;
        }
    }
    #undef GB_LOAD
    #undef GB_WRITE
    #undef GA_GLDS
    #undef G_COMPUTE
}

// ---------------- fused tail: t[b,:] reduce + out = x + y + sum_r t_r x_b ----------------
__global__ __launch_bounds__(256) void tail_kernel(const float* __restrict__ x,
                                                   const float* __restrict__ w,
                                                   float* __restrict__ out) {
    const int b = blockIdx.x;
    const int tid = threadIdx.x;
    const float* wa = w + (size_t)b * NOUT;            // x_a half
    const float4 xv = ((const float4*)(x + (size_t)b * DD))[tid];
    const float xs[4] = {xv.x, xv.y, xv.z, xv.w};

    float acc[RR] = {};
    #pragma unroll
    for (int i = 0; i < 4; i++) {
        const int c = tid * 4 + i;
        const float4 w0 = *(const float4*)&wa[c * RR];
        const float4 w1 = *(const float4*)&wa[c * RR + 4];
        acc[0] = fmaf(xs[i], w0.x, acc[0]);
        acc[1] = fmaf(xs[i], w0.y, acc[1]);
        acc[2] = fmaf(xs[i], w0.z, acc[2]);
        acc[3] = fmaf(xs[i], w0.w, acc[3]);
        acc[4] = fmaf(xs[i], w1.x, acc[4]);
        acc[5] = fmaf(xs[i], w1.y, acc[5]);
        acc[6] = fmaf(xs[i], w1.z, acc[6]);
        acc[7] = fmaf(xs[i], w1.w, acc[7]);
    }
    __shared__ float red[4][RR];
    __shared__ float trs[RR];
    const int wid = tid >> 6, lane = tid & 63;
    #pragma unroll
    for (int r = 0; r < RR; r++) {
        float vv = acc[r];
        #pragma unroll
        for (int off = 32; off; off >>= 1) vv += __shfl_down(vv, off);
        if (lane == 0) red[wid][r] = vv;
    }
    __syncthreads();
    if (tid < RR) trs[tid] = red[0][tid] + red[1][tid] + red[2][tid] + red[3][tid];
    __syncthreads();

    float tr[RR];
    #pragma unroll
    for (int r = 0; r < RR; r++) tr[r] = trs[r];

    const float* wb = wa + DD * RR;                    // x_b half
    const int o0 = tid * 4;
    const float4 yv = *(const float4*)&out[(size_t)b * DD + o0];  // y = x@base in place

    float vals[4];
    #pragma unroll
    for (int i = 0; i < 4; i++) {
        const float4 w0 = *(const float4*)&wb[(o0 + i) * RR];
        const float4 w1 = *(const float4*)&wb[(o0 + i) * RR + 4];
        vals[i] = tr[0] * w0.x + tr[1] * w0.y + tr[2] * w0.z + tr[3] * w0.w
                + tr[4] * w1.x + tr[5] * w1.y + tr[6] * w1.z + tr[7] * w1.w;
    }
    float4 o;
    o.x = xv.x + yv.x + vals[0];
    o.y = xv.y + yv.y + vals[1];
    o.z = xv.z + yv.z + vals[2];
    o.w = xv.w + yv.w + vals[3];
    *(float4*)&out[(size_t)b * DD + o0] = o;
}

extern "C" void kernel_launch(void* const* d_in, const int* in_sizes, int n_in,
                              void* d_out, int out_size, void* d_ws, size_t ws_size,
                              hipStream_t stream) {
    const float* x     = (const float*)d_in[0];
    const float* ada   = (const float*)d_in[1];
    const float* base  = (const float*)d_in[2];
    const float* gamma = (const float*)d_in[3];
    const float* beta  = (const float*)d_in[4];
    const float* W1    = (const float*)d_in[5];
    const float* b1    = (const float*)d_in[6];
    const float* W2    = (const float*)d_in[7];
    const float* b2    = (const float*)d_in[8];
    float* out = (float*)d_out;

    // ws layout: 19,922,944 B total (within proven footprint)
    char* wsb = (char*)d_ws;
    float* w = (float*)(wsb);                                   // 16,777,216
    unsigned short* h_hi = (unsigned short*)(wsb + 16777216);   //    524,288
    unsigned short* h_lo = (unsigned short*)(wsb + 17301504);   //    524,288
    unsigned short* x_hi = (unsigned short*)(wsb + 17825792);   //    524,288
    unsigned short* x_lo = (unsigned short*)(wsb + 18350080);   //    524,288
    unsigned short* c_hi = (unsigned short*)(wsb + 18874368);   //    524,288
    unsigned short* c_lo = (unsigned short*)(wsb + 19398656);   //    524,288

    // 1) LayerNorm -> cond planes; split x -> planes
    ln_split_kernel<<<BB, 256, 0, stream>>>(ada, x, gamma, beta, c_hi, c_lo, x_hi, x_lo);

    // 2) z=0: out = x@base (in place) ; z=1: h = gelu(cond@W1+b1) -> planes
    gemm_small<<<dim3(1024 / 64, BB / 32, 2), 256, 0, stream>>>(
        x_hi, x_lo, c_hi, c_lo, base, W1, b1, out, h_hi, h_lo);

    // 3) w = h @ W2 + b2  (dominant GEMM; 256 blocks, 4 waves of 64x64)
    gemm_big<<<dim3(NOUT / 128, BB / 128), 256, 0, stream>>>(h_hi, h_lo, W2, b2, w);

    // 4) fused: t reduce + out = x + y + lora
    tail_kernel<<<BB, 256, 0, stream>>>(x, w, out);
}

// Round 5
// 186.550 us; speedup vs baseline: 1.1154x; 1.0842x over previous
//
#include <hip/hip_runtime.h>
#include <math.h>

// Problem constants
#define BB 256      // batch
#define DD 1024     // feat dim
#define AA 1024     // ada dim
#define RR 8        // rank
#define II 1024     // inter dim
#define NOUT (2*DD*RR)  // 16384
#define LN_EPS 1e-5f

typedef __attribute__((ext_vector_type(8))) short bf16x8;            // 8 bf16
typedef __attribute__((ext_vector_type(8))) unsigned short ushort8;  // 16B store
typedef __attribute__((ext_vector_type(4))) float f32x4;             // MFMA acc

typedef const __attribute__((address_space(1))) unsigned int gu32_t;
typedef __attribute__((address_space(3))) unsigned int lu32_t;

// async global->LDS, 16B/lane; LDS base wave-uniform (HW adds lane*16)
__device__ __forceinline__ void glds16(void* lds, const void* g) {
    __builtin_amdgcn_global_load_lds((gu32_t*)g, (lu32_t*)lds, 16, 0, 0);
}

__device__ __forceinline__ f32x4 mfma16(bf16x8 a, bf16x8 b, f32x4 c) {
    return __builtin_amdgcn_mfma_f32_16x16x32_bf16(a, b, c, 0, 0, 0);
}

__device__ __forceinline__ unsigned short f2bf(float x) {
    unsigned int u = __float_as_uint(x);
    unsigned int r = (u + 0x7fffu + ((u >> 16) & 1u)) >> 16;
    return (unsigned short)r;
}
__device__ __forceinline__ float bf2f(unsigned short b) {
    return __uint_as_float(((unsigned int)b) << 16);
}
__device__ __forceinline__ void split2(float x, unsigned short& hi, unsigned short& lo) {
    hi = f2bf(x);
    lo = f2bf(x - bf2f(hi));
}

__device__ __forceinline__ float gelu_exact(float v) {
    return 0.5f * v * (1.0f + erff(v * 0.70710678118654752f));
}

// ---------------- LayerNorm + split(cond), split(x) ----------------
__global__ __launch_bounds__(256) void ln_split_kernel(const float* __restrict__ ada,
                                                       const float* __restrict__ xp,
                                                       const float* __restrict__ gamma,
                                                       const float* __restrict__ beta,
                                                       unsigned short* __restrict__ c_hi,
                                                       unsigned short* __restrict__ c_lo,
                                                       unsigned short* __restrict__ x_hi,
                                                       unsigned short* __restrict__ x_lo) {
    const int b = blockIdx.x;
    const int tid = threadIdx.x;
    const float4 v = ((const float4*)(ada + (size_t)b * AA))[tid];

    float s  = v.x + v.y + v.z + v.w;
    float ss = v.x * v.x + v.y * v.y + v.z * v.z + v.w * v.w;
    #pragma unroll
    for (int off = 32; off; off >>= 1) {
        s  += __shfl_down(s, off);
        ss += __shfl_down(ss, off);
    }
    __shared__ float red[2][4];
    const int wid = tid >> 6, lane = tid & 63;
    if (lane == 0) { red[0][wid] = s; red[1][wid] = ss; }
    __syncthreads();
    __shared__ float stats[2];
    if (tid == 0) {
        float S  = red[0][0] + red[0][1] + red[0][2] + red[0][3];
        float SS = red[1][0] + red[1][1] + red[1][2] + red[1][3];
        float mu  = S * (1.0f / AA);
        float var = SS * (1.0f / AA) - mu * mu;
        stats[0] = mu;
        stats[1] = rsqrtf(var + LN_EPS);
    }
    __syncthreads();
    const float mu = stats[0], inv = stats[1];
    const float4 g  = ((const float4*)gamma)[tid];
    const float4 be = ((const float4*)beta)[tid];
    float o[4];
    o[0] = (v.x - mu) * inv * g.x + be.x;
    o[1] = (v.y - mu) * inv * g.y + be.y;
    o[2] = (v.z - mu) * inv * g.z + be.z;
    o[3] = (v.w - mu) * inv * g.w + be.w;
    ushort4 H, L;
    split2(o[0], H.x, L.x); split2(o[1], H.y, L.y);
    split2(o[2], H.z, L.z); split2(o[3], H.w, L.w);
    ((ushort4*)(c_hi + (size_t)b * AA))[tid] = H;
    ((ushort4*)(c_lo + (size_t)b * AA))[tid] = L;

    const float4 xv = ((const float4*)(xp + (size_t)b * DD))[tid];
    split2(xv.x, H.x, L.x); split2(xv.y, H.y, L.y);
    split2(xv.z, H.z, L.z); split2(xv.w, H.w, L.w);
    ((ushort4*)(x_hi + (size_t)b * DD))[tid] = H;
    ((ushort4*)(x_lo + (size_t)b * DD))[tid] = L;
}

// ---------------- small GEMMs: BM=32, BN=64, BK=64, grid (16,8,2), 16 iters ----------------
// z=0: out = x @ base (fp32) ; z=1: h = gelu(cond @ W1 + b1) -> bf16 planes
// A LDS [pl2][mb2][kidx8][16][16B] = 8KB/buf ; B [pl2][nb4][kidx8][16][16B] = 16KB/buf
// 4 waves; wave tile 32 M x 16 N (ni = wid).
__global__ __launch_bounds__(256) void gemm_small(const unsigned short* __restrict__ x_hi,
                                                  const unsigned short* __restrict__ x_lo,
                                                  const unsigned short* __restrict__ c_hi,
                                                  const unsigned short* __restrict__ c_lo,
                                                  const float* __restrict__ base,
                                                  const float* __restrict__ W1,
                                                  const float* __restrict__ b1,
                                                  float* __restrict__ outy,
                                                  unsigned short* __restrict__ h_hi,
                                                  unsigned short* __restrict__ h_lo) {
    __shared__ __align__(16) unsigned short As[2][4096];   // 8KB per buf
    __shared__ __align__(16) unsigned short Bs[2][8192];   // 16KB per buf

    const int z = blockIdx.z;
    const unsigned short* __restrict__ Ahi = z ? c_hi : x_hi;
    const unsigned short* __restrict__ Alo = z ? c_lo : x_lo;
    const float* __restrict__ Bsrc = z ? W1 : base;

    const int tid = threadIdx.x;
    const int bn = blockIdx.x * 64;
    const int bm = blockIdx.y * 32;
    const int wid = tid >> 6, l = tid & 63;
    const int kg = l >> 4, lr16 = (l & 15) * 16;

    f32x4 acc[2];
    acc[0] = (f32x4)0.0f; acc[1] = (f32x4)0.0f;

    const int sn = tid & 63;                   // B col
    const int s_nb = sn >> 4, s_l16 = (sn & 15) * 16;

    float v[2][8];

    #define SB_LOAD(K0)                                                          \
        _Pragma("unroll")                                                        \
        for (int h = 0; h < 2; h++) {                                            \
            const int c2 = (tid >> 6) * 2 + h;   /* kidx chunk 0..7 */           \
            _Pragma("unroll")                                                    \
            for (int j = 0; j < 8; j++)                                          \
                v[h][j] = Bsrc[(size_t)((K0) + c2 * 8 + j) * 1024 + bn + sn];    \
        }

    #define SB_WRITE(BUF)                                                        \
        _Pragma("unroll")                                                        \
        for (int h = 0; h < 2; h++) {                                            \
            const int c2 = (tid >> 6) * 2 + h;                                   \
            ushort8 H, L;                                                        \
            _Pragma("unroll")                                                    \
            for (int j = 0; j < 8; j++) { unsigned short hh, ll;                 \
                split2(v[h][j], hh, ll); H[j] = hh; L[j] = ll; }                 \
            *(ushort8*)((char*)Bs[BUF] + ((0*4 + s_nb)*8 + c2)*256 + s_l16) = H; \
            *(ushort8*)((char*)Bs[BUF] + ((1*4 + s_nb)*8 + c2)*256 + s_l16) = L; \
        }

    #define SA_GLDS(BUF, K0)                                                     \
        _Pragma("unroll")                                                        \
        for (int c = 0; c < 2; c++) {                                            \
            const int ch = wid * 2 + c;          /* 0..7 */                      \
            const int pl = ch >> 2, sub = ch & 3;                                \
            const int mb = sub >> 1, half = sub & 1;                             \
            const unsigned short* src = (pl ? Alo : Ahi)                         \
                + (size_t)(bm + mb * 16 + (l & 15)) * 1024 + (K0) + half * 32 + kg * 8; \
            glds16((char*)As[BUF] + (pl*2 + mb)*2048 + half*1024, src);          \
        }

    #define S_COMPUTE(BUF)                                                       \
        {                                                                        \
            _Pragma("unroll")                                                    \
            for (int s = 0; s < 2; s++) {                                        \
                bf16x8 a[2][2], bbf[2];                                          \
                _Pragma("unroll")                                                \
                for (int pl = 0; pl < 2; pl++) {                                 \
                    _Pragma("unroll")                                            \
                    for (int mi = 0; mi < 2; mi++)                               \
                        a[pl][mi] = *(const bf16x8*)((const char*)As[BUF] +      \
                            ((pl*2 + mi)*8 + s*4 + kg)*256 + lr16);              \
                    bbf[pl] = *(const bf16x8*)((const char*)Bs[BUF] +            \
                            ((pl*4 + wid)*8 + s*4 + kg)*256 + lr16);             \
                }                                                                \
                __builtin_amdgcn_s_setprio(1);                                   \
                _Pragma("unroll")                                                \
                for (int mi = 0; mi < 2; mi++) {                                 \
                    acc[mi] = mfma16(a[0][mi], bbf[0], acc[mi]);                 \
                    acc[mi] = mfma16(a[0][mi], bbf[1], acc[mi]);                 \
                    acc[mi] = mfma16(a[1][mi], bbf[0], acc[mi]);                 \
                }                                                                \
                __builtin_amdgcn_s_setprio(0);                                   \
            }                                                                    \
        }

    SB_LOAD(0);
    SA_GLDS(0, 0);
    SB_WRITE(0);
    __syncthreads();

    int cur = 0;
    for (int t = 0; t < 16; ++t) {
        if (t < 15) {
            const int k0n = (t + 1) * 64;
            SB_LOAD(k0n);
            SA_GLDS(cur ^ 1, k0n);
        }
        S_COMPUTE(cur);
        if (t < 15) {
            SB_WRITE(cur ^ 1);
        }
        __syncthreads();
        cur ^= 1;
    }

    // epilogue
    #pragma unroll
    for (int mi = 0; mi < 2; mi++) {
        const int row0 = bm + mi * 16 + kg * 4;
        const int col  = bn + wid * 16 + (l & 15);
        #pragma unroll
        for (int j = 0; j < 4; j++) {
            float val = acc[mi][j];
            if (z == 0) {
                outy[(size_t)(row0 + j) * 1024 + col] = val;
            } else {
                float g = gelu_exact(val + b1[col]);
                unsigned short hi, lo;
                split2(g, hi, lo);
                h_hi[(size_t)(row0 + j) * 1024 + col] = hi;
                h_lo[(size_t)(row0 + j) * 1024 + col] = lo;
            }
        }
    }
    #undef SB_LOAD
    #undef SB_WRITE
    #undef SA_GLDS
    #undef S_COMPUTE
}

// ---------------- big GEMM: BM=128, BN=64, BK=32, grid 512 (2 blocks/CU) ----------------
// M=256, N=16384, K=1024. 4 waves (2x2), wave tile 64x32.
// A LDS [pl2][mb8][kg4][16][16B] = 16KB/buf ; B [pl2][nb4][kg4][16][16B] = 8KB/buf; 48KB total.
// XCD swizzle: consecutive orig-bids (the 2 M-blocks of one W2 panel) -> same XCD.
__global__ __launch_bounds__(256) void gemm_big(const unsigned short* __restrict__ Ahi,
                                                const unsigned short* __restrict__ Alo,
                                                const float* __restrict__ Bm,
                                                const float* __restrict__ bias,
                                                float* __restrict__ Cm) {
    __shared__ __align__(16) unsigned short As[2][8192];   // 16KB per buf
    __shared__ __align__(16) unsigned short Bs[2][4096];   // 8KB per buf

    const int orig = blockIdx.x;                 // 0..511
    const int swz  = ((orig & 7) << 6) + (orig >> 3);   // bijective, 512 % 8 == 0
    const int bn = (swz >> 1) * 64;
    const int bm = (swz & 1) * 128;

    const int tid = threadIdx.x;
    const int wid = tid >> 6, l = tid & 63;
    const int wm = wid >> 1, wn = wid & 1;       // wave tile 64x32
    const int kg = l >> 4, lr16 = (l & 15) * 16;

    f32x4 acc[4][2];
    #pragma unroll
    for (int i = 0; i < 4; i++) { acc[i][0] = (f32x4)0.0f; acc[i][1] = (f32x4)0.0f; }

    const int sn = tid & 63;                     // B col
    const int skc = tid >> 6;                    // kidx chunk 0..3
    const int s_nb = sn >> 4, s_l16 = (sn & 15) * 16;

    float v[8];

    #define GB_LOAD(K0)                                                          \
        _Pragma("unroll")                                                        \
        for (int j = 0; j < 8; j++)                                              \
            v[j] = Bm[(size_t)((K0) + skc * 8 + j) * NOUT + bn + sn];

    #define GB_WRITE(BUF)                                                        \
        {                                                                        \
            ushort8 H, L;                                                        \
            _Pragma("unroll")                                                    \
            for (int j = 0; j < 8; j++) { unsigned short hh, ll;                 \
                split2(v[j], hh, ll); H[j] = hh; L[j] = ll; }                    \
            *(ushort8*)((char*)Bs[BUF] + ((0*4 + s_nb)*4 + skc)*256 + s_l16) = H;\
            *(ushort8*)((char*)Bs[BUF] + ((1*4 + s_nb)*4 + skc)*256 + s_l16) = L;\
        }

    #define GA_GLDS(BUF, K0)                                                     \
        _Pragma("unroll")                                                        \
        for (int c = 0; c < 4; c++) {                                            \
            const int ch = wid * 4 + c;          /* 0..15 */                     \
            const int pl = ch >> 3, mb = ch & 7;                                 \
            const unsigned short* src = (pl ? Alo : Ahi)                         \
                + (size_t)(bm + mb * 16 + (l & 15)) * II + (K0) + kg * 8;        \
            glds16((char*)As[BUF] + ch * 1024, src);                             \
        }

    #define G_COMPUTE(BUF)                                                       \
        {                                                                        \
            bf16x8 a[2][4], bbf[2][2];                                           \
            _Pragma("unroll")                                                    \
            for (int pl = 0; pl < 2; pl++) {                                     \
                _Pragma("unroll")                                                \
                for (int mi = 0; mi < 4; mi++)                                   \
                    a[pl][mi] = *(const bf16x8*)((const char*)As[BUF] +          \
                        ((pl*8 + wm*4 + mi)*4 + kg)*256 + lr16);                 \
                _Pragma("unroll")                                                \
                for (int ni = 0; ni < 2; ni++)                                   \
                    bbf[pl][ni] = *(const bf16x8*)((const char*)Bs[BUF] +        \
                        ((pl*4 + wn*2 + ni)*4 + kg)*256 + lr16);                 \
            }                                                                    \
            __builtin_amdgcn_s_setprio(1);                                       \
            _Pragma("unroll")                                                    \
            for (int mi = 0; mi < 4; mi++) {                                     \
                _Pragma("unroll")                                                \
                for (int ni = 0; ni < 2; ni++) {                                 \
                    acc[mi][ni] = mfma16(a[0][mi], bbf[0][ni], acc[mi][ni]);     \
                    acc[mi][ni] = mfma16(a[0][mi], bbf[1][ni], acc[mi][ni]);     \
                    acc[mi][ni] = mfma16(a[1][mi], bbf[0][ni], acc[mi][ni]);     \
                }                                                                \
            }                                                                    \
            __builtin_amdgcn_s_setprio(0);                                       \
        }

    GB_LOAD(0);
    GA_GLDS(0, 0);
    GB_WRITE(0);
    __syncthreads();

    int cur = 0;
    for (int t = 0; t < 32; ++t) {
        if (t < 31) {
            const int k0n = (t + 1) * 32;
            GB_LOAD(k0n);
            GA_GLDS(cur ^ 1, k0n);
        }
        G_COMPUTE(cur);
        if (t < 31) {
            GB_WRITE(cur ^ 1);
        }
        __syncthreads();
        cur ^= 1;
    }

    // epilogue: + bias
    #pragma unroll
    for (int mi = 0; mi < 4; mi++) {
        #pragma unroll
        for (int ni = 0; ni < 2; ni++) {
            const int row0 = bm + wm * 64 + mi * 16 + kg * 4;
            const int col  = bn + wn * 32 + ni * 16 + (l & 15);
            const float bv = bias[col];
            #pragma unroll
            for (int j = 0; j < 4; j++)
                Cm[(size_t)(row0 + j) * NOUT + col] = acc[mi][ni][j] + bv;
        }
    }
    #undef GB_LOAD
    #undef GB_WRITE
    #undef GA_GLDS
    #undef G_COMPUTE
}

// ---------------- fused tail: t[b,:] reduce + out = x + y + sum_r t_r x_b ----------------
__global__ __launch_bounds__(256) void tail_kernel(const float* __restrict__ x,
                                                   const float* __restrict__ w,
                                                   float* __restrict__ out) {
    const int b = blockIdx.x;
    const int tid = threadIdx.x;
    const float* wa = w + (size_t)b * NOUT;            // x_a half
    const float4 xv = ((const float4*)(x + (size_t)b * DD))[tid];
    const float xs[4] = {xv.x, xv.y, xv.z, xv.w};

    float acc[RR] = {};
    #pragma unroll
    for (int i = 0; i < 4; i++) {
        const int c = tid * 4 + i;
        const float4 w0 = *(const float4*)&wa[c * RR];
        const float4 w1 = *(const float4*)&wa[c * RR + 4];
        acc[0] = fmaf(xs[i], w0.x, acc[0]);
        acc[1] = fmaf(xs[i], w0.y, acc[1]);
        acc[2] = fmaf(xs[i], w0.z, acc[2]);
        acc[3] = fmaf(xs[i], w0.w, acc[3]);
        acc[4] = fmaf(xs[i], w1.x, acc[4]);
        acc[5] = fmaf(xs[i], w1.y, acc[5]);
        acc[6] = fmaf(xs[i], w1.z, acc[6]);
        acc[7] = fmaf(xs[i], w1.w, acc[7]);
    }
    __shared__ float red[4][RR];
    __shared__ float trs[RR];
    const int wid = tid >> 6, lane = tid & 63;
    #pragma unroll
    for (int r = 0; r < RR; r++) {
        float vv = acc[r];
        #pragma unroll
        for (int off = 32; off; off >>= 1) vv += __shfl_down(vv, off);
        if (lane == 0) red[wid][r] = vv;
    }
    __syncthreads();
    if (tid < RR) trs[tid] = red[0][tid] + red[1][tid] + red[2][tid] + red[3][tid];
    __syncthreads();

    float tr[RR];
    #pragma unroll
    for (int r = 0; r < RR; r++) tr[r] = trs[r];

    const float* wb = wa + DD * RR;                    // x_b half
    const int o0 = tid * 4;
    const float4 yv = *(const float4*)&out[(size_t)b * DD + o0];  // y = x@base in place

    float vals[4];
    #pragma unroll
    for (int i = 0; i < 4; i++) {
        const float4 w0 = *(const float4*)&wb[(o0 + i) * RR];
        const float4 w1 = *(const float4*)&wb[(o0 + i) * RR + 4];
        vals[i] = tr[0] * w0.x + tr[1] * w0.y + tr[2] * w0.z + tr[3] * w0.w
                + tr[4] * w1.x + tr[5] * w1.y + tr[6] * w1.z + tr[7] * w1.w;
    }
    float4 o;
    o.x = xv.x + yv.x + vals[0];
    o.y = xv.y + yv.y + vals[1];
    o.z = xv.z + yv.z + vals[2];
    o.w = xv.w + yv.w + vals[3];
    *(float4*)&out[(size_t)b * DD + o0] = o;
}

extern "C" void kernel_launch(void* const* d_in, const int* in_sizes, int n_in,
                              void* d_out, int out_size, void* d_ws, size_t ws_size,
                              hipStream_t stream) {
    const float* x     = (const float*)d_in[0];
    const float* ada   = (const float*)d_in[1];
    const float* base  = (const float*)d_in[2];
    const float* gamma = (const float*)d_in[3];
    const float* beta  = (const float*)d_in[4];
    const float* W1    = (const float*)d_in[5];
    const float* b1    = (const float*)d_in[6];
    const float* W2    = (const float*)d_in[7];
    const float* b2    = (const float*)d_in[8];
    float* out = (float*)d_out;

    // ws layout: 19,922,944 B total (within proven footprint)
    char* wsb = (char*)d_ws;
    float* w = (float*)(wsb);                                   // 16,777,216
    unsigned short* h_hi = (unsigned short*)(wsb + 16777216);   //    524,288
    unsigned short* h_lo = (unsigned short*)(wsb + 17301504);   //    524,288
    unsigned short* x_hi = (unsigned short*)(wsb + 17825792);   //    524,288
    unsigned short* x_lo = (unsigned short*)(wsb + 18350080);   //    524,288
    unsigned short* c_hi = (unsigned short*)(wsb + 18874368);   //    524,288
    unsigned short* c_lo = (unsigned short*)(wsb + 19398656);   //    524,288

    // 1) LayerNorm -> cond planes; split x -> planes
    ln_split_kernel<<<BB, 256, 0, stream>>>(ada, x, gamma, beta, c_hi, c_lo, x_hi, x_lo);

    // 2) z=0: out = x@base (in place) ; z=1: h = gelu(cond@W1+b1) -> planes
    gemm_small<<<dim3(1024 / 64, BB / 32, 2), 256, 0, stream>>>(
        x_hi, x_lo, c_hi, c_lo, base, W1, b1, out, h_hi, h_lo);

    // 3) w = h @ W2 + b2  (512 blocks, 2/CU residency)
    gemm_big<<<512, 256, 0, stream>>>(h_hi, h_lo, W2, b2, w);

    // 4) fused: t reduce + out = x + y + lora
    tail_kernel<<<BB, 256, 0, stream>>>(x, w, out);
}

// Round 6
// 178.010 us; speedup vs baseline: 1.1689x; 1.0480x over previous
//
#include <hip/hip_runtime.h>
#include <math.h>

// Problem constants
#define BB 256      // batch
#define DD 1024     // feat dim
#define AA 1024     // ada dim
#define RR 8        // rank
#define II 1024     // inter dim
#define NOUT (2*DD*RR)  // 16384
#define LN_EPS 1e-5f

typedef __attribute__((ext_vector_type(8))) short bf16x8;            // 8 bf16
typedef __attribute__((ext_vector_type(8))) unsigned short ushort8;  // 16B store
typedef __attribute__((ext_vector_type(4))) float f32x4;             // MFMA acc

typedef const __attribute__((address_space(1))) unsigned int gu32_t;
typedef __attribute__((address_space(3))) unsigned int lu32_t;

// async global->LDS, 16B/lane; LDS base wave-uniform (HW adds lane*16)
__device__ __forceinline__ void glds16(void* lds, const void* g) {
    __builtin_amdgcn_global_load_lds((gu32_t*)g, (lu32_t*)lds, 16, 0, 0);
}

__device__ __forceinline__ f32x4 mfma16(bf16x8 a, bf16x8 b, f32x4 c) {
    return __builtin_amdgcn_mfma_f32_16x16x32_bf16(a, b, c, 0, 0, 0);
}

__device__ __forceinline__ unsigned short f2bf(float x) {
    unsigned int u = __float_as_uint(x);
    unsigned int r = (u + 0x7fffu + ((u >> 16) & 1u)) >> 16;
    return (unsigned short)r;
}
__device__ __forceinline__ float bf2f(unsigned short b) {
    return __uint_as_float(((unsigned int)b) << 16);
}
__device__ __forceinline__ void split2(float x, unsigned short& hi, unsigned short& lo) {
    hi = f2bf(x);
    lo = f2bf(x - bf2f(hi));
}

__device__ __forceinline__ float gelu_exact(float v) {
    return 0.5f * v * (1.0f + erff(v * 0.70710678118654752f));
}

// region-boundary waits (raw barrier; counted semantics preserved)
__device__ __forceinline__ void region_top_wait() {
    asm volatile("s_waitcnt vmcnt(0) lgkmcnt(0)" ::: "memory");
    __builtin_amdgcn_sched_barrier(0);
    __builtin_amdgcn_s_barrier();
    __builtin_amdgcn_sched_barrier(0);
}
__device__ __forceinline__ void region_end_wait() {
    asm volatile("s_waitcnt lgkmcnt(0)" ::: "memory");
    __builtin_amdgcn_sched_barrier(0);
}

// ============ LayerNorm + split -> TILED planes ============
// x/c tiled image per (mb32 = b>>5, kt64 = k>>6): 8KB
//   [pl2][mbh2][kidx8][row16][16B]; off = ((pl*2+mbh)*8 + kidx)*256 + (b&15)*16 + (k&7)*2
__global__ __launch_bounds__(256) void ln_split_kernel(const float* __restrict__ ada,
                                                       const float* __restrict__ xp,
                                                       const float* __restrict__ gamma,
                                                       const float* __restrict__ beta,
                                                       char* __restrict__ c_t,
                                                       char* __restrict__ x_t) {
    const int b = blockIdx.x;
    const int tid = threadIdx.x;
    const float4 v = ((const float4*)(ada + (size_t)b * AA))[tid];

    float s  = v.x + v.y + v.z + v.w;
    float ss = v.x * v.x + v.y * v.y + v.z * v.z + v.w * v.w;
    #pragma unroll
    for (int off = 32; off; off >>= 1) {
        s  += __shfl_down(s, off);
        ss += __shfl_down(ss, off);
    }
    __shared__ float red[2][4];
    const int wid = tid >> 6, lane = tid & 63;
    if (lane == 0) { red[0][wid] = s; red[1][wid] = ss; }
    __syncthreads();
    __shared__ float stats[2];
    if (tid == 0) {
        float S  = red[0][0] + red[0][1] + red[0][2] + red[0][3];
        float SS = red[1][0] + red[1][1] + red[1][2] + red[1][3];
        float mu  = S * (1.0f / AA);
        float var = SS * (1.0f / AA) - mu * mu;
        stats[0] = mu;
        stats[1] = rsqrtf(var + LN_EPS);
    }
    __syncthreads();
    const float mu = stats[0], inv = stats[1];
    const float4 g  = ((const float4*)gamma)[tid];
    const float4 be = ((const float4*)beta)[tid];

    const int k0 = tid * 4;
    const int mbh = (b >> 4) & 1;
    const size_t img = ((size_t)(b >> 5) * 16 + (k0 >> 6)) * 8192;
    const int inoff = ((k0 >> 3) & 7) * 256 + (b & 15) * 16 + (k0 & 7) * 2;

    float o[4];
    o[0] = (v.x - mu) * inv * g.x + be.x;
    o[1] = (v.y - mu) * inv * g.y + be.y;
    o[2] = (v.z - mu) * inv * g.z + be.z;
    o[3] = (v.w - mu) * inv * g.w + be.w;
    ushort4 H, L;
    split2(o[0], H.x, L.x); split2(o[1], H.y, L.y);
    split2(o[2], H.z, L.z); split2(o[3], H.w, L.w);
    *(ushort4*)(c_t + img + (0 * 2 + mbh) * 2048 + inoff) = H;
    *(ushort4*)(c_t + img + (1 * 2 + mbh) * 2048 + inoff) = L;

    const float4 xv = ((const float4*)(xp + (size_t)b * DD))[tid];
    split2(xv.x, H.x, L.x); split2(xv.y, H.y, L.y);
    split2(xv.z, H.z, L.z); split2(xv.w, H.w, L.w);
    *(ushort4*)(x_t + img + (0 * 2 + mbh) * 2048 + inoff) = H;
    *(ushort4*)(x_t + img + (1 * 2 + mbh) * 2048 + inoff) = L;
}

// ============ small GEMMs: BM=32, BN=64, BK=64, 16 regions ============
// z=0: out = x @ base (fp32) ; z=1: h = gelu(cond @ W1 + b1) -> h tiled planes
// A LDS img [pl2][mb2][kidx8][16][16B] = 8KB (linear glds from tiled x/c)
// B LDS img [pl2][nb4][kidx8][16][16B] = 16KB (staged: load->split->ds_write)
// 4 waves; wave tile 32M x 16N (wid = n-quarter).
__global__ __launch_bounds__(256) void gemm_small(const char* __restrict__ x_t,
                                                  const char* __restrict__ c_t,
                                                  const float* __restrict__ base,
                                                  const float* __restrict__ W1,
                                                  const float* __restrict__ b1,
                                                  float* __restrict__ outy,
                                                  char* __restrict__ h_t) {
    __shared__ __align__(16) char As[2][8192];
    __shared__ __align__(16) char Bs[2][16384];

    const int z = blockIdx.z;
    const char* __restrict__ At = z ? c_t : x_t;
    const float* __restrict__ Bsrc = z ? W1 : base;

    const int tid = threadIdx.x;
    const int bn = blockIdx.x * 64;
    const int bm = blockIdx.y * 32;
    const int wid = tid >> 6, l = tid & 63;
    const int kg = l >> 4, lr16 = (l & 15) * 16;

    f32x4 acc[2];
    acc[0] = (f32x4)0.0f; acc[1] = (f32x4)0.0f;

    const int sn = tid & 63;                 // B col
    const int sk0 = (tid >> 6) * 16;         // 16 k's per thread
    const int s_nb = sn >> 4, s_l16 = (sn & 15) * 16;

    float v[16];

    #define SB_LOAD(KT)                                                          \
        _Pragma("unroll")                                                        \
        for (int j = 0; j < 16; j++)                                             \
            v[j] = Bsrc[(size_t)((KT) * 64 + sk0 + j) * 1024 + bn + sn];

    #define SB_WRITE(BUF)                                                        \
        _Pragma("unroll")                                                        \
        for (int h2 = 0; h2 < 2; h2++) {                                         \
            const int kidx = (sk0 >> 3) + h2;                                    \
            ushort8 H, L;                                                        \
            _Pragma("unroll")                                                    \
            for (int j = 0; j < 8; j++) { unsigned short hh, ll;                 \
                split2(v[h2 * 8 + j], hh, ll); H[j] = hh; L[j] = ll; }           \
            *(ushort8*)(Bs[BUF] + ((0*4 + s_nb)*8 + kidx)*256 + s_l16) = H;      \
            *(ushort8*)(Bs[BUF] + ((1*4 + s_nb)*8 + kidx)*256 + s_l16) = L;      \
        }

    #define SA_GLDS(BUF, KT)                                                     \
        {                                                                        \
            const char* ib = At + ((size_t)(bm >> 5) * 16 + (KT)) * 8192;        \
            _Pragma("unroll")                                                    \
            for (int c = 0; c < 2; c++) {                                        \
                const int ch = wid * 2 + c;                                      \
                glds16(As[BUF] + ch * 1024, ib + ch * 1024 + l * 16);            \
            }                                                                    \
        }

    #define S_COMPUTE(BUF)                                                       \
        _Pragma("unroll")                                                        \
        for (int s2 = 0; s2 < 2; s2++) {                                         \
            bf16x8 a[2][2], bbf[2];                                              \
            _Pragma("unroll")                                                    \
            for (int pl = 0; pl < 2; pl++) {                                     \
                _Pragma("unroll")                                                \
                for (int mi = 0; mi < 2; mi++)                                   \
                    a[pl][mi] = *(const bf16x8*)(As[BUF] +                       \
                        ((pl*2 + mi)*8 + s2*4 + kg)*256 + lr16);                 \
                bbf[pl] = *(const bf16x8*)(Bs[BUF] +                             \
                        ((pl*4 + wid)*8 + s2*4 + kg)*256 + lr16);                \
            }                                                                    \
            _Pragma("unroll")                                                    \
            for (int mi = 0; mi < 2; mi++) {                                     \
                acc[mi] = mfma16(a[0][mi], bbf[0], acc[mi]);                     \
                acc[mi] = mfma16(a[0][mi], bbf[1], acc[mi]);                     \
                acc[mi] = mfma16(a[1][mi], bbf[0], acc[mi]);                     \
            }                                                                    \
        }

    // prologue: stage tile 0 into buf 0
    SB_LOAD(0);
    SA_GLDS(0, 0);
    SB_WRITE(0);

    for (int t = 0; t < 16; ++t) {
        const int cur = t & 1;
        region_top_wait();
        if (t < 15) {
            SB_LOAD(t + 1);          // early issue: latency hides under compute
            SA_GLDS(cur ^ 1, t + 1);
        }
        S_COMPUTE(cur);
        if (t < 15) {
            SB_WRITE(cur ^ 1);       // compiler emits counted vmcnt for v[]
        }
        region_end_wait();
    }

    // epilogue
    #pragma unroll
    for (int mi = 0; mi < 2; mi++) {
        const int row0 = bm + mi * 16 + kg * 4;
        const int col  = bn + wid * 16 + (l & 15);
        #pragma unroll
        for (int j = 0; j < 4; j++) {
            float val = acc[mi][j];
            const int row = row0 + j;
            if (z == 0) {
                outy[(size_t)row * 1024 + col] = val;
            } else {
                float g = gelu_exact(val + b1[col]);
                unsigned short hi, lo;
                split2(g, hi, lo);
                // h tiled image per (mb128=row>>7, kt32=col>>5): 16KB
                char* ib = h_t + ((size_t)(row >> 7) * 32 + (col >> 5)) * 16384;
                const int inoff = (((row >> 4) & 7) * 4 + ((col >> 3) & 3)) * 256
                                + (row & 15) * 16 + (col & 7) * 2;
                *(unsigned short*)(ib + 0 * 8192 + inoff) = hi;
                *(unsigned short*)(ib + 1 * 8192 + inoff) = lo;
            }
        }
    }
    #undef SB_LOAD
    #undef SB_WRITE
    #undef SA_GLDS
    #undef S_COMPUTE
}

// ============ big GEMM: BM=128, BN=128, BK=32, 32 regions ============
// grid (128, 2) = 256 blocks, 512 thr = 8 waves (2M x 4N), wave 64x32.
// A LDS img [pl2][mb8][kg4][16][16B] = 16KB (linear glds from h tiled)
// B LDS img [pl2][nb8][kg4][16][16B] = 16KB (staged W2)
__global__ __launch_bounds__(512) void gemm_big(const char* __restrict__ h_t,
                                                const float* __restrict__ Bm,
                                                const float* __restrict__ bias,
                                                float* __restrict__ Cm) {
    __shared__ __align__(16) char As[2][16384];
    __shared__ __align__(16) char Bs[2][16384];

    const int tid = threadIdx.x;
    const int bn = blockIdx.x * 128;
    const int bm = blockIdx.y * 128;
    const int wid = tid >> 6, l = tid & 63;
    const int wm = wid >> 2, wn = wid & 3;   // wave tile 64x32
    const int kg = l >> 4, lr16 = (l & 15) * 16;

    f32x4 acc[4][2];
    #pragma unroll
    for (int i = 0; i < 4; i++) { acc[i][0] = (f32x4)0.0f; acc[i][1] = (f32x4)0.0f; }

    const int sn = tid & 127;                // B col
    const int skg = tid >> 7;                // kg chunk 0..3 (8 k's)
    const int s_nb = sn >> 4, s_l16 = (sn & 15) * 16;

    float v[8];

    #define GB_LOAD(KT)                                                          \
        _Pragma("unroll")                                                        \
        for (int j = 0; j < 8; j++)                                              \
            v[j] = Bm[(size_t)((KT) * 32 + skg * 8 + j) * NOUT + bn + sn];

    #define GB_WRITE(BUF)                                                        \
        {                                                                        \
            ushort8 H, L;                                                        \
            _Pragma("unroll")                                                    \
            for (int j = 0; j < 8; j++) { unsigned short hh, ll;                 \
                split2(v[j], hh, ll); H[j] = hh; L[j] = ll; }                    \
            *(ushort8*)(Bs[BUF] + ((0*8 + s_nb)*4 + skg)*256 + s_l16) = H;       \
            *(ushort8*)(Bs[BUF] + ((1*8 + s_nb)*4 + skg)*256 + s_l16) = L;       \
        }

    #define GA_GLDS(BUF, KT)                                                     \
        {                                                                        \
            const char* ib = h_t + ((size_t)(bm >> 7) * 32 + (KT)) * 16384;      \
            _Pragma("unroll")                                                    \
            for (int c = 0; c < 2; c++) {                                        \
                const int ch = wid * 2 + c;                                      \
                glds16(As[BUF] + ch * 1024, ib + ch * 1024 + l * 16);            \
            }                                                                    \
        }

    #define G_COMPUTE(BUF)                                                       \
        {                                                                        \
            bf16x8 a[2][4], bbf[2][2];                                           \
            _Pragma("unroll")                                                    \
            for (int pl = 0; pl < 2; pl++) {                                     \
                _Pragma("unroll")                                                \
                for (int mi = 0; mi < 4; mi++)                                   \
                    a[pl][mi] = *(const bf16x8*)(As[BUF] +                       \
                        ((pl*8 + wm*4 + mi)*4 + kg)*256 + lr16);                 \
                _Pragma("unroll")                                                \
                for (int ni = 0; ni < 2; ni++)                                   \
                    bbf[pl][ni] = *(const bf16x8*)(Bs[BUF] +                     \
                        ((pl*8 + wn*2 + ni)*4 + kg)*256 + lr16);                 \
            }                                                                    \
            __builtin_amdgcn_s_setprio(1);                                       \
            _Pragma("unroll")                                                    \
            for (int mi = 0; mi < 4; mi++) {                                     \
                _Pragma("unroll")                                                \
                for (int ni = 0; ni < 2; ni++) {                                 \
                    acc[mi][ni] = mfma16(a[0][mi], bbf[0][ni], acc[mi][ni]);     \
                    acc[mi][ni] = mfma16(a[0][mi], bbf[1][ni], acc[mi][ni]);     \
                    acc[mi][ni] = mfma16(a[1][mi], bbf[0][ni], acc[mi][ni]);     \
                }                                                                \
            }                                                                    \
            __builtin_amdgcn_s_setprio(0);                                       \
        }

    // prologue
    GB_LOAD(0);
    GA_GLDS(0, 0);
    GB_WRITE(0);

    for (int t = 0; t < 32; ++t) {
        const int cur = t & 1;
        region_top_wait();
        if (t < 31) {
            GB_LOAD(t + 1);
            GA_GLDS(cur ^ 1, t + 1);
        }
        G_COMPUTE(cur);
        if (t < 31) {
            GB_WRITE(cur ^ 1);
        }
        region_end_wait();
    }

    // epilogue: + bias
    #pragma unroll
    for (int mi = 0; mi < 4; mi++) {
        #pragma unroll
        for (int ni = 0; ni < 2; ni++) {
            const int row0 = bm + wm * 64 + mi * 16 + kg * 4;
            const int col  = bn + wn * 32 + ni * 16 + (l & 15);
            const float bv = bias[col];
            #pragma unroll
            for (int j = 0; j < 4; j++)
                Cm[(size_t)(row0 + j) * NOUT + col] = acc[mi][ni][j] + bv;
        }
    }
    #undef GB_LOAD
    #undef GB_WRITE
    #undef GA_GLDS
    #undef G_COMPUTE
}

// ============ fused tail: t[b,:] reduce + out = x + y + sum_r t_r x_b ============
__global__ __launch_bounds__(256) void tail_kernel(const float* __restrict__ x,
                                                   const float* __restrict__ w,
                                                   float* __restrict__ out) {
    const int b = blockIdx.x;
    const int tid = threadIdx.x;
    const float* wa = w + (size_t)b * NOUT;            // x_a half
    const float4 xv = ((const float4*)(x + (size_t)b * DD))[tid];
    const float xs[4] = {xv.x, xv.y, xv.z, xv.w};

    float acc[RR] = {};
    #pragma unroll
    for (int i = 0; i < 4; i++) {
        const int c = tid * 4 + i;
        const float4 w0 = *(const float4*)&wa[c * RR];
        const float4 w1 = *(const float4*)&wa[c * RR + 4];
        acc[0] = fmaf(xs[i], w0.x, acc[0]);
        acc[1] = fmaf(xs[i], w0.y, acc[1]);
        acc[2] = fmaf(xs[i], w0.z, acc[2]);
        acc[3] = fmaf(xs[i], w0.w, acc[3]);
        acc[4] = fmaf(xs[i], w1.x, acc[4]);
        acc[5] = fmaf(xs[i], w1.y, acc[5]);
        acc[6] = fmaf(xs[i], w1.z, acc[6]);
        acc[7] = fmaf(xs[i], w1.w, acc[7]);
    }
    __shared__ float red[4][RR];
    __shared__ float trs[RR];
    const int wid = tid >> 6, lane = tid & 63;
    #pragma unroll
    for (int r = 0; r < RR; r++) {
        float vv = acc[r];
        #pragma unroll
        for (int off = 32; off; off >>= 1) vv += __shfl_down(vv, off);
        if (lane == 0) red[wid][r] = vv;
    }
    __syncthreads();
    if (tid < RR) trs[tid] = red[0][tid] + red[1][tid] + red[2][tid] + red[3][tid];
    __syncthreads();

    float tr[RR];
    #pragma unroll
    for (int r = 0; r < RR; r++) tr[r] = trs[r];

    const float* wb = wa + DD * RR;                    // x_b half
    const int o0 = tid * 4;
    const float4 yv = *(const float4*)&out[(size_t)b * DD + o0];  // y = x@base in place

    float vals[4];
    #pragma unroll
    for (int i = 0; i < 4; i++) {
        const float4 w0 = *(const float4*)&wb[(o0 + i) * RR];
        const float4 w1 = *(const float4*)&wb[(o0 + i) * RR + 4];
        vals[i] = tr[0] * w0.x + tr[1] * w0.y + tr[2] * w0.z + tr[3] * w0.w
                + tr[4] * w1.x + tr[5] * w1.y + tr[6] * w1.z + tr[7] * w1.w;
    }
    float4 o;
    o.x = xv.x + yv.x + vals[0];
    o.y = xv.y + yv.y + vals[1];
    o.z = xv.z + yv.z + vals[2];
    o.w = xv.w + yv.w + vals[3];
    *(float4*)&out[(size_t)b * DD + o0] = o;
}

extern "C" void kernel_launch(void* const* d_in, const int* in_sizes, int n_in,
                              void* d_out, int out_size, void* d_ws, size_t ws_size,
                              hipStream_t stream) {
    const float* x     = (const float*)d_in[0];
    const float* ada   = (const float*)d_in[1];
    const float* base  = (const float*)d_in[2];
    const float* gamma = (const float*)d_in[3];
    const float* beta  = (const float*)d_in[4];
    const float* W1    = (const float*)d_in[5];
    const float* b1    = (const float*)d_in[6];
    const float* W2    = (const float*)d_in[7];
    const float* b2    = (const float*)d_in[8];
    float* out = (float*)d_out;

    // ws layout: 19,922,944 B total (within proven footprint)
    char* wsb = (char*)d_ws;
    float* w  = (float*)(wsb);            // 16,777,216  (h@W2+b2)
    char* h_t = wsb + 16777216;           //  1,048,576  h tiled hi/lo images
    char* x_t = wsb + 17825792;           //  1,048,576  x tiled hi/lo images
    char* c_t = wsb + 18874368;           //  1,048,576  cond tiled hi/lo images

    // 1) LayerNorm -> cond tiled planes; split x -> tiled planes
    ln_split_kernel<<<BB, 256, 0, stream>>>(ada, x, gamma, beta, c_t, x_t);

    // 2) z=0: out = x@base (in place) ; z=1: h = gelu(cond@W1+b1) -> h tiled
    gemm_small<<<dim3(1024 / 64, BB / 32, 2), 256, 0, stream>>>(
        x_t, c_t, base, W1, b1, out, h_t);

    // 3) w = h @ W2 + b2  (256 blocks, 8 waves, counted-wait pipeline)
    gemm_big<<<dim3(NOUT / 128, BB / 128), 512, 0, stream>>>(h_t, W2, b2, w);

    // 4) fused: t reduce + out = x + y + lora
    tail_kernel<<<BB, 256, 0, stream>>>(x, w, out);
}